// Round 6
// baseline (1389.108 us; speedup 1.0000x reference)
//
#include <hip/hip_runtime.h>

#define N_NODES 100000
#define N_EDGES 1600000
#define N_GRAPHS 256
#define NB 1563              // ceil(100000 / 64) buckets of 64 nodes
#define BCAP 1280            // per-bucket fixed capacity (mean 1024, +8 sigma)
#define SBLOCKS 128          // stage blocks; 12500 edges each

// ---------------- stage: two-pass LDS-cursor bucket scatter -----------------
__global__ __launch_bounds__(256) void stage_kernel(const int* __restrict__ src,
                                                    const int* __restrict__ dst,
                                                    int* __restrict__ bucket_cur,
                                                    unsigned* __restrict__ pairbuf) {
    __shared__ int lcnt[NB];
    __shared__ int lcur[NB];
    const int tid = threadIdx.x;
    const int per = (N_EDGES + SBLOCKS - 1) / SBLOCKS;   // 12500
    const int e0 = blockIdx.x * per;
    const int e1 = min(e0 + per, N_EDGES);

    for (int i = tid; i < NB; i += 256) lcnt[i] = 0;
    __syncthreads();
    for (int e = e0 + tid; e < e1; e += 256)
        atomicAdd(&lcnt[dst[e] >> 6], 1);
    __syncthreads();
    for (int i = tid; i < NB; i += 256) {
        int c = lcnt[i];
        lcur[i] = c ? atomicAdd(&bucket_cur[i], c) : 0;   // reserve [base, base+c)
    }
    __syncthreads();
    for (int e = e0 + tid; e < e1; e += 256) {
        int d = dst[e];
        int b = d >> 6;
        int p = atomicAdd(&lcur[b], 1);                   // LDS cursor
        if (p < BCAP)
            pairbuf[(size_t)b * BCAP + p] =
                ((unsigned)(d & 63) << 17) | (unsigned)src[e];
    }
}

// ---------------- scan over bucket totals -> bucket_off ---------------------
#define BVPT 7   // 256*7 = 1792 >= NB
__global__ __launch_bounds__(256) void scan_buckets_kernel(const int* __restrict__ bucket_cur,
                                                           int* __restrict__ bucket_off) {
    __shared__ int tsum[256];
    int tid = threadIdx.x;
    int v[BVPT];
    int s = 0;
#pragma unroll
    for (int j = 0; j < BVPT; ++j) {
        int idx = tid * BVPT + j;
        v[j] = (idx < NB) ? min(bucket_cur[idx], BCAP) : 0;
        s += v[j];
    }
    tsum[tid] = s;
    __syncthreads();
    for (int off = 1; off < 256; off <<= 1) {
        int y = (tid >= off) ? tsum[tid - off] : 0;
        __syncthreads();
        tsum[tid] += y;
        __syncthreads();
    }
    int run = (tid > 0) ? tsum[tid - 1] : 0;
#pragma unroll
    for (int j = 0; j < BVPT; ++j) {
        int idx = tid * BVPT + j;
        if (idx < NB) bucket_off[idx] = run;
        run += v[j];
    }
    if (tid == 255) bucket_off[NB] = tsum[255];
}

// ---------------- per-bucket counting sort -> csr/row_off/dinv --------------
__global__ __launch_bounds__(256) void localsort_kernel(const unsigned* __restrict__ pairbuf,
                                                        const int* __restrict__ bucket_cur,
                                                        const int* __restrict__ bucket_off,
                                                        int* __restrict__ csr_src,
                                                        int* __restrict__ row_off,
                                                        float* __restrict__ dinv) {
    __shared__ int ldeg[64];
    __shared__ int loff[64];
    __shared__ int lcur[64];
    int tid = threadIdx.x;
    int b = blockIdx.x;
    int cnt = min(bucket_cur[b], BCAP);
    int base = bucket_off[b];
    const unsigned* pb = pairbuf + (size_t)b * BCAP;
    int n0 = b << 6;

    if (tid < 64) ldeg[tid] = 0;
    __syncthreads();
    for (int i = tid; i < cnt; i += 256)
        atomicAdd(&ldeg[pb[i] >> 17], 1);
    __syncthreads();
    if (tid < 64) loff[tid] = ldeg[tid];
    __syncthreads();
    for (int off = 1; off < 64; off <<= 1) {
        int y = 0;
        if (tid < 64 && tid >= off) y = loff[tid - off];
        __syncthreads();
        if (tid < 64) loff[tid] += y;
        __syncthreads();
    }
    if (tid < 64) {
        int ex = loff[tid] - ldeg[tid];   // exclusive prefix
        lcur[tid] = ex;
        int n = n0 + tid;
        if (n < N_NODES) {
            row_off[n] = base + ex;
            dinv[n] = rsqrtf((float)ldeg[tid] + 1.0f);
        }
    }
    __syncthreads();
    for (int i = tid; i < cnt; i += 256) {
        unsigned w = pb[i];
        int dl = w >> 17;
        int s = (int)(w & 0x1FFFFu);
        int p = atomicAdd(&lcur[dl], 1);
        csr_src[base + p] = s;
    }
}

// ---------------- GEMM: HT[N,128] = (X @ W) * dinv[row] ---------------------
#define BM 128
#define KC 32
__global__ __launch_bounds__(256) void gemm_kernel(const float* __restrict__ X,
                                                   const float* __restrict__ W,
                                                   const float* __restrict__ dinv,
                                                   float* __restrict__ HT) {
    __shared__ float Xt[KC][132];
    __shared__ float Wl[KC][128];
    const int tid = threadIdx.x;
    const int row0 = blockIdx.x * BM;
    const int cg = tid & 15;
    const int rg = tid >> 4;
    const int c_lo = cg * 4, r_lo = rg * 4;

    float acc[8][8];
#pragma unroll
    for (int i = 0; i < 8; ++i)
#pragma unroll
        for (int j = 0; j < 8; ++j) acc[i][j] = 0.0f;

    for (int kb = 0; kb < 128; kb += KC) {
        __syncthreads();
#pragma unroll
        for (int i = 0; i < 4; ++i) {
            int idx = tid * 4 + i * 1024;        // 0..4095
            int r = idx >> 5;
            int kk = idx & 31;
            int rr = row0 + r;
            if (rr >= N_NODES) rr = N_NODES - 1;
            const float4 v = *(const float4*)&X[(size_t)rr * 128 + kb + kk];
            Xt[kk + 0][r] = v.x;
            Xt[kk + 1][r] = v.y;
            Xt[kk + 2][r] = v.z;
            Xt[kk + 3][r] = v.w;
        }
#pragma unroll
        for (int i = 0; i < 4; ++i) {
            int idx = tid * 4 + i * 1024;
            int r = idx >> 7;
            int c = idx & 127;
            *(float4*)&Wl[r][c] = *(const float4*)&W[(size_t)(kb + r) * 128 + c];
        }
        __syncthreads();
#pragma unroll 4
        for (int k = 0; k < KC; ++k) {
            float4 a0 = *(float4*)&Xt[k][r_lo];
            float4 a1 = *(float4*)&Xt[k][64 + r_lo];
            float4 b0 = *(float4*)&Wl[k][c_lo];
            float4 b1 = *(float4*)&Wl[k][64 + c_lo];
            float a[8] = {a0.x, a0.y, a0.z, a0.w, a1.x, a1.y, a1.z, a1.w};
            float b[8] = {b0.x, b0.y, b0.z, b0.w, b1.x, b1.y, b1.z, b1.w};
#pragma unroll
            for (int i = 0; i < 8; ++i)
#pragma unroll
                for (int j = 0; j < 8; ++j)
                    acc[i][j] = fmaf(a[i], b[j], acc[i][j]);
        }
    }
#pragma unroll
    for (int i = 0; i < 8; ++i) {
        int ri = (i < 4) ? (r_lo + i) : (64 + r_lo + i - 4);
        int rr = row0 + ri;
        if (rr < N_NODES) {
            float di = dinv[rr];
            float4 o0 = make_float4(acc[i][0] * di, acc[i][1] * di,
                                    acc[i][2] * di, acc[i][3] * di);
            float4 o1 = make_float4(acc[i][4] * di, acc[i][5] * di,
                                    acc[i][6] * di, acc[i][7] * di);
            *(float4*)&HT[(size_t)rr * 128 + c_lo] = o0;
            *(float4*)&HT[(size_t)rr * 128 + 64 + c_lo] = o1;
        }
    }
}

// ---------------- chunked gather: XCD-pinned 8-float feature slices ---------
// chunk = blockIdx&7 -> all blocks of chunk c land on XCD c (round-robin
// dispatch, T1-measured). Slice of ht for one chunk = 100K*32B = 3.2 MB
// < 4 MB per-XCD L2 -> random src reads are L2-resident. Two launches per
// layer (fhalf=0,64) keep one slice per XCD live at a time.
#define NSEG 256
#define NPS 391   // ceil(N_NODES / NSEG)
__global__ __launch_bounds__(256) void gatherc_kernel(const int* __restrict__ row_off,
                                                      const int* __restrict__ csr_src,
                                                      const float* __restrict__ ht,
                                                      const float* __restrict__ dinv,
                                                      const float* __restrict__ bias,
                                                      float* __restrict__ Y,
                                                      int fhalf) {
    const int c   = blockIdx.x & 7;
    const int seg = blockIdx.x >> 3;
    const int f0  = fhalf + c * 8 + (threadIdx.x & 1) * 4;
    const int n0  = seg * NPS;
    const int n1  = min(n0 + NPS, N_NODES);
    const float4 bb = *(const float4*)&bias[f0];
    for (int n = n0 + (threadIdx.x >> 1); n < n1; n += 128) {
        int e0 = row_off[n];
        int e1 = (n < N_NODES - 1) ? row_off[n + 1] : N_EDGES;
        float4 acc = *(const float4*)&ht[(size_t)n * 128 + f0];   // self-loop
        for (int e = e0; e < e1; ++e) {
            int s = csr_src[e];
            float4 v = *(const float4*)&ht[(size_t)s * 128 + f0];
            acc.x += v.x; acc.y += v.y; acc.z += v.z; acc.w += v.w;
        }
        float di = dinv[n];
        float4 o;
        o.x = fmaxf(acc.x * di + bb.x, 0.0f);
        o.y = fmaxf(acc.y * di + bb.y, 0.0f);
        o.z = fmaxf(acc.z * di + bb.z, 0.0f);
        o.w = fmaxf(acc.w * di + bb.w, 0.0f);
        *(float4*)&Y[(size_t)n * 128 + f0] = o;
    }
}

// ---------------- mean-pool: run-length accumulate over sorted batch --------
#define NODES_PER_GROUP 100
__global__ __launch_bounds__(256) void pool_kernel(const float* __restrict__ Y,
                                                   const int* __restrict__ batch,
                                                   float* __restrict__ pooled,
                                                   float* __restrict__ counts) {
    int g = (blockIdx.x * 256 + threadIdx.x) >> 5;
    int lane = threadIdx.x & 31;
    int f = lane * 4;
    int n0 = g * NODES_PER_GROUP;
    if (n0 >= N_NODES) return;
    int n1 = min(n0 + NODES_PER_GROUP, N_NODES);
    int cur = batch[n0];
    float4 acc = make_float4(0, 0, 0, 0);
    float cnt = 0.0f;
    for (int n = n0; n < n1; ++n) {
        int bid = batch[n];
        if (bid != cur) {
            float* p = &pooled[cur * 128 + f];
            atomicAdd(p + 0, acc.x); atomicAdd(p + 1, acc.y);
            atomicAdd(p + 2, acc.z); atomicAdd(p + 3, acc.w);
            if (lane == 0) atomicAdd(&counts[cur], cnt);
            acc = make_float4(0, 0, 0, 0); cnt = 0.0f; cur = bid;
        }
        float4 v = *(const float4*)&Y[(size_t)n * 128 + f];
        acc.x += v.x; acc.y += v.y; acc.z += v.z; acc.w += v.w;
        cnt += 1.0f;
    }
    float* p = &pooled[cur * 128 + f];
    atomicAdd(p + 0, acc.x); atomicAdd(p + 1, acc.y);
    atomicAdd(p + 2, acc.z); atomicAdd(p + 3, acc.w);
    if (lane == 0) atomicAdd(&counts[cur], cnt);
}

// ---------------- head: out[g] = dot(pooled[g], w_out)/count + b_out --------
__global__ __launch_bounds__(256) void out_kernel(const float* __restrict__ pooled,
                                                  const float* __restrict__ counts,
                                                  const float* __restrict__ w_out,
                                                  const float* __restrict__ b_out,
                                                  float* __restrict__ out) {
    int gph = threadIdx.x;
    float c = fmaxf(counts[gph], 1.0f);
    float s = 0.0f;
    for (int f = 0; f < 128; ++f) s += pooled[gph * 128 + f] * w_out[f];
    out[gph] = s / c + b_out[0];
}

extern "C" void kernel_launch(void* const* d_in, const int* in_sizes, int n_in,
                              void* d_out, int out_size, void* d_ws, size_t ws_size,
                              hipStream_t stream) {
    const float* x     = (const float*)d_in[0];
    const int*   edge  = (const int*)d_in[1];   // [2, E]
    const int*   batch = (const int*)d_in[2];
    const float* w1    = (const float*)d_in[3];
    const float* b1    = (const float*)d_in[4];
    const float* w2    = (const float*)d_in[5];
    const float* b2    = (const float*)d_in[6];
    const float* w_out = (const float*)d_in[7];
    const float* b_out = (const float*)d_in[8];
    float* out = (float*)d_out;

    char* ws = (char*)d_ws;
    size_t off = 0;
    auto alloc = [&](size_t bytes) {
        void* p = ws + off;
        off += (bytes + 511) & ~(size_t)511;
        return p;
    };
    const size_t FEAT_BYTES = (size_t)N_NODES * 128 * 4;     // 51.2 MB
    float*    buf0       = (float*)alloc(FEAT_BYTES);        // HT
    float*    buf1       = (float*)alloc(FEAT_BYTES);        // Y (aliases pairbuf)
    unsigned* pairbuf    = (unsigned*)buf1;                  // NB*BCAP*4 = 8.0 MB, dead before first gather
    float*    dinv       = (float*)alloc(N_NODES * 4);
    int*      row_off    = (int*)alloc(N_NODES * 4);
    int*      csr_src    = (int*)alloc(N_EDGES * 4);         // 6.4 MB
    int*      bucket_cur = (int*)alloc((NB + 1) * 4);
    int*      bucket_off = (int*)alloc((NB + 1) * 4);
    float*    pooled     = (float*)alloc(N_GRAPHS * 128 * 4);
    float*    counts     = (float*)alloc(N_GRAPHS * 4);

    const int* src = edge;
    const int* dst = edge + N_EDGES;

    hipMemsetAsync(bucket_cur, 0, (NB + 1) * 4, stream);
    hipMemsetAsync(pooled, 0, N_GRAPHS * 128 * 4, stream);
    hipMemsetAsync(counts, 0, N_GRAPHS * 4, stream);

    // ----- bucketed CSR build (no per-edge global atomics) -----
    stage_kernel<<<SBLOCKS, 256, 0, stream>>>(src, dst, bucket_cur, pairbuf);
    scan_buckets_kernel<<<1, 256, 0, stream>>>(bucket_cur, bucket_off);
    localsort_kernel<<<NB, 256, 0, stream>>>(pairbuf, bucket_cur, bucket_off,
                                             csr_src, row_off, dinv);

    // ----- layer 1 -----
    int gblocks = (N_NODES + BM - 1) / BM;
    gemm_kernel<<<gblocks, 256, 0, stream>>>(x, w1, dinv, buf0);
    gatherc_kernel<<<NSEG * 8, 256, 0, stream>>>(row_off, csr_src, buf0, dinv, b1, buf1, 0);
    gatherc_kernel<<<NSEG * 8, 256, 0, stream>>>(row_off, csr_src, buf0, dinv, b1, buf1, 64);

    // ----- layer 2 -----
    gemm_kernel<<<gblocks, 256, 0, stream>>>(buf1, w2, dinv, buf0);
    gatherc_kernel<<<NSEG * 8, 256, 0, stream>>>(row_off, csr_src, buf0, dinv, b2, buf1, 0);
    gatherc_kernel<<<NSEG * 8, 256, 0, stream>>>(row_off, csr_src, buf0, dinv, b2, buf1, 64);

    // ----- pool + head -----
    int ngroups = (N_NODES + NODES_PER_GROUP - 1) / NODES_PER_GROUP;
    pool_kernel<<<(ngroups * 32 + 255) / 256, 256, 0, stream>>>(buf1, batch, pooled, counts);
    out_kernel<<<1, 256, 0, stream>>>(pooled, counts, w_out, b_out, out);
}

// Round 7
// 427.317 us; speedup vs baseline: 3.2508x; 3.2508x over previous
//
#include <hip/hip_runtime.h>
#include <hip/hip_fp16.h>

#define N_NODES 100000
#define N_EDGES 1600000
#define N_GRAPHS 256
#define NB 1563              // ceil(100000 / 64) buckets of 64 nodes
#define BCAP 1280            // per-bucket fixed capacity (mean 1024, +8 sigma)
#define SBLOCKS 128          // stage blocks; 12500 edges each

// ---------------- stage: two-pass LDS-cursor bucket scatter -----------------
__global__ __launch_bounds__(256) void stage_kernel(const int* __restrict__ src,
                                                    const int* __restrict__ dst,
                                                    int* __restrict__ bucket_cur,
                                                    unsigned* __restrict__ pairbuf) {
    __shared__ int lcnt[NB];
    __shared__ int lcur[NB];
    const int tid = threadIdx.x;
    const int per = (N_EDGES + SBLOCKS - 1) / SBLOCKS;   // 12500
    const int e0 = blockIdx.x * per;
    const int e1 = min(e0 + per, N_EDGES);

    for (int i = tid; i < NB; i += 256) lcnt[i] = 0;
    __syncthreads();
    for (int e = e0 + tid; e < e1; e += 256)
        atomicAdd(&lcnt[dst[e] >> 6], 1);
    __syncthreads();
    for (int i = tid; i < NB; i += 256) {
        int c = lcnt[i];
        lcur[i] = c ? atomicAdd(&bucket_cur[i], c) : 0;   // reserve [base, base+c)
    }
    __syncthreads();
    for (int e = e0 + tid; e < e1; e += 256) {
        int d = dst[e];
        int b = d >> 6;
        int p = atomicAdd(&lcur[b], 1);                   // LDS cursor
        if (p < BCAP)
            pairbuf[(size_t)b * BCAP + p] =
                ((unsigned)(d & 63) << 17) | (unsigned)src[e];
    }
}

// ---------------- scan over bucket totals -> bucket_off ---------------------
#define BVPT 7   // 256*7 = 1792 >= NB
__global__ __launch_bounds__(256) void scan_buckets_kernel(const int* __restrict__ bucket_cur,
                                                           int* __restrict__ bucket_off) {
    __shared__ int tsum[256];
    int tid = threadIdx.x;
    int v[BVPT];
    int s = 0;
#pragma unroll
    for (int j = 0; j < BVPT; ++j) {
        int idx = tid * BVPT + j;
        v[j] = (idx < NB) ? min(bucket_cur[idx], BCAP) : 0;
        s += v[j];
    }
    tsum[tid] = s;
    __syncthreads();
    for (int off = 1; off < 256; off <<= 1) {
        int y = (tid >= off) ? tsum[tid - off] : 0;
        __syncthreads();
        tsum[tid] += y;
        __syncthreads();
    }
    int run = (tid > 0) ? tsum[tid - 1] : 0;
#pragma unroll
    for (int j = 0; j < BVPT; ++j) {
        int idx = tid * BVPT + j;
        if (idx < NB) bucket_off[idx] = run;
        run += v[j];
    }
    if (tid == 255) bucket_off[NB] = tsum[255];
}

// ---------------- per-bucket counting sort -> csr/row_off/dinv --------------
__global__ __launch_bounds__(256) void localsort_kernel(const unsigned* __restrict__ pairbuf,
                                                        const int* __restrict__ bucket_cur,
                                                        const int* __restrict__ bucket_off,
                                                        int* __restrict__ csr_src,
                                                        int* __restrict__ row_off,
                                                        float* __restrict__ dinv) {
    __shared__ int ldeg[64];
    __shared__ int loff[64];
    __shared__ int lcur[64];
    int tid = threadIdx.x;
    int b = blockIdx.x;
    int cnt = min(bucket_cur[b], BCAP);
    int base = bucket_off[b];
    const unsigned* pb = pairbuf + (size_t)b * BCAP;
    int n0 = b << 6;

    if (tid < 64) ldeg[tid] = 0;
    __syncthreads();
    for (int i = tid; i < cnt; i += 256)
        atomicAdd(&ldeg[pb[i] >> 17], 1);
    __syncthreads();
    if (tid < 64) loff[tid] = ldeg[tid];
    __syncthreads();
    for (int off = 1; off < 64; off <<= 1) {
        int y = 0;
        if (tid < 64 && tid >= off) y = loff[tid - off];
        __syncthreads();
        if (tid < 64) loff[tid] += y;
        __syncthreads();
    }
    if (tid < 64) {
        int ex = loff[tid] - ldeg[tid];   // exclusive prefix
        lcur[tid] = ex;
        int n = n0 + tid;
        if (n < N_NODES) {
            row_off[n] = base + ex;
            dinv[n] = rsqrtf((float)ldeg[tid] + 1.0f);
        }
    }
    __syncthreads();
    for (int i = tid; i < cnt; i += 256) {
        unsigned w = pb[i];
        int dl = w >> 17;
        int s = (int)(w & 0x1FFFFu);
        int p = atomicAdd(&lcur[dl], 1);
        csr_src[base + p] = s;
    }
}

// ---------------- GEMM: HT16[N,128] = fp16((X @ W) * dinv[row]) -------------
#define BM 128
#define KC 32
__device__ __forceinline__ unsigned pack2(float a, float b) {
    __half2 h = __floats2half2_rn(a, b);
    return *reinterpret_cast<unsigned*>(&h);
}
__global__ __launch_bounds__(256) void gemm_kernel(const float* __restrict__ X,
                                                   const float* __restrict__ W,
                                                   const float* __restrict__ dinv,
                                                   __half* __restrict__ HT) {
    __shared__ float Xt[KC][132];
    __shared__ float Wl[KC][128];
    const int tid = threadIdx.x;
    const int row0 = blockIdx.x * BM;
    const int cg = tid & 15;
    const int rg = tid >> 4;
    const int c_lo = cg * 4, r_lo = rg * 4;

    float acc[8][8];
#pragma unroll
    for (int i = 0; i < 8; ++i)
#pragma unroll
        for (int j = 0; j < 8; ++j) acc[i][j] = 0.0f;

    for (int kb = 0; kb < 128; kb += KC) {
        __syncthreads();
#pragma unroll
        for (int i = 0; i < 4; ++i) {
            int idx = tid * 4 + i * 1024;        // 0..4095
            int r = idx >> 5;
            int kk = idx & 31;
            int rr = row0 + r;
            if (rr >= N_NODES) rr = N_NODES - 1;
            const float4 v = *(const float4*)&X[(size_t)rr * 128 + kb + kk];
            Xt[kk + 0][r] = v.x;
            Xt[kk + 1][r] = v.y;
            Xt[kk + 2][r] = v.z;
            Xt[kk + 3][r] = v.w;
        }
#pragma unroll
        for (int i = 0; i < 4; ++i) {
            int idx = tid * 4 + i * 1024;
            int r = idx >> 7;
            int c = idx & 127;
            *(float4*)&Wl[r][c] = *(const float4*)&W[(size_t)(kb + r) * 128 + c];
        }
        __syncthreads();
#pragma unroll 4
        for (int k = 0; k < KC; ++k) {
            float4 a0 = *(float4*)&Xt[k][r_lo];
            float4 a1 = *(float4*)&Xt[k][64 + r_lo];
            float4 b0 = *(float4*)&Wl[k][c_lo];
            float4 b1 = *(float4*)&Wl[k][64 + c_lo];
            float a[8] = {a0.x, a0.y, a0.z, a0.w, a1.x, a1.y, a1.z, a1.w};
            float b[8] = {b0.x, b0.y, b0.z, b0.w, b1.x, b1.y, b1.z, b1.w};
#pragma unroll
            for (int i = 0; i < 8; ++i)
#pragma unroll
                for (int j = 0; j < 8; ++j)
                    acc[i][j] = fmaf(a[i], b[j], acc[i][j]);
        }
    }
#pragma unroll
    for (int i = 0; i < 8; ++i) {
        int ri = (i < 4) ? (r_lo + i) : (64 + r_lo + i - 4);
        int rr = row0 + ri;
        if (rr < N_NODES) {
            float di = dinv[rr];
            uint2 o0, o1;
            o0.x = pack2(acc[i][0] * di, acc[i][1] * di);
            o0.y = pack2(acc[i][2] * di, acc[i][3] * di);
            o1.x = pack2(acc[i][4] * di, acc[i][5] * di);
            o1.y = pack2(acc[i][6] * di, acc[i][7] * di);
            *(uint2*)&HT[(size_t)rr * 128 + c_lo] = o0;
            *(uint2*)&HT[(size_t)rr * 128 + 64 + c_lo] = o1;
        }
    }
}

// ---------------- gather: Y[n] = relu(dinv[n]*(sum ht16[src] + ht16[n]) + b)
// 32 lanes per node; each lane owns 4 features (8 B fp16). Row = 256 B,
// fully coalesced. fp32 accumulation.
__global__ __launch_bounds__(256) void gather_kernel(const int* __restrict__ row_off,
                                                     const int* __restrict__ csr_src,
                                                     const __half* __restrict__ ht,
                                                     const float* __restrict__ dinv,
                                                     const float* __restrict__ b,
                                                     float* __restrict__ Y) {
    int t = blockIdx.x * 256 + threadIdx.x;
    int n = t >> 5;
    if (n >= N_NODES) return;
    int f = (t & 31) * 4;
    int e0 = row_off[n];
    int e1 = (n < N_NODES - 1) ? row_off[n + 1] : N_EDGES;
    const __half* htf = ht + f;

    float acc0 = 0.f, acc1 = 0.f, acc2 = 0.f, acc3 = 0.f;
    {   // self-loop term
        uint2 w = *(const uint2*)&htf[(size_t)n * 128];
        float2 p0 = __half22float2(*reinterpret_cast<__half2*>(&w.x));
        float2 p1 = __half22float2(*reinterpret_cast<__half2*>(&w.y));
        acc0 = p0.x; acc1 = p0.y; acc2 = p1.x; acc3 = p1.y;
    }
    for (int e = e0; e < e1; ++e) {
        int s = csr_src[e];
        uint2 w = *(const uint2*)&htf[(size_t)s * 128];
        float2 p0 = __half22float2(*reinterpret_cast<__half2*>(&w.x));
        float2 p1 = __half22float2(*reinterpret_cast<__half2*>(&w.y));
        acc0 += p0.x; acc1 += p0.y; acc2 += p1.x; acc3 += p1.y;
    }
    float di = dinv[n];
    float4 bb = *(const float4*)&b[f];
    float4 o;
    o.x = fmaxf(acc0 * di + bb.x, 0.0f);
    o.y = fmaxf(acc1 * di + bb.y, 0.0f);
    o.z = fmaxf(acc2 * di + bb.z, 0.0f);
    o.w = fmaxf(acc3 * di + bb.w, 0.0f);
    *(float4*)&Y[(size_t)n * 128 + f] = o;
}

// ---------------- mean-pool: run-length accumulate over sorted batch --------
#define NODES_PER_GROUP 100
__global__ __launch_bounds__(256) void pool_kernel(const float* __restrict__ Y,
                                                   const int* __restrict__ batch,
                                                   float* __restrict__ pooled,
                                                   float* __restrict__ counts) {
    int g = (blockIdx.x * 256 + threadIdx.x) >> 5;
    int lane = threadIdx.x & 31;
    int f = lane * 4;
    int n0 = g * NODES_PER_GROUP;
    if (n0 >= N_NODES) return;
    int n1 = min(n0 + NODES_PER_GROUP, N_NODES);
    int cur = batch[n0];
    float4 acc = make_float4(0, 0, 0, 0);
    float cnt = 0.0f;
    for (int n = n0; n < n1; ++n) {
        int bid = batch[n];
        if (bid != cur) {
            float* p = &pooled[cur * 128 + f];
            atomicAdd(p + 0, acc.x); atomicAdd(p + 1, acc.y);
            atomicAdd(p + 2, acc.z); atomicAdd(p + 3, acc.w);
            if (lane == 0) atomicAdd(&counts[cur], cnt);
            acc = make_float4(0, 0, 0, 0); cnt = 0.0f; cur = bid;
        }
        float4 v = *(const float4*)&Y[(size_t)n * 128 + f];
        acc.x += v.x; acc.y += v.y; acc.z += v.z; acc.w += v.w;
        cnt += 1.0f;
    }
    float* p = &pooled[cur * 128 + f];
    atomicAdd(p + 0, acc.x); atomicAdd(p + 1, acc.y);
    atomicAdd(p + 2, acc.z); atomicAdd(p + 3, acc.w);
    if (lane == 0) atomicAdd(&counts[cur], cnt);
}

// ---------------- head: out[g] = dot(pooled[g], w_out)/count + b_out --------
__global__ __launch_bounds__(256) void out_kernel(const float* __restrict__ pooled,
                                                  const float* __restrict__ counts,
                                                  const float* __restrict__ w_out,
                                                  const float* __restrict__ b_out,
                                                  float* __restrict__ out) {
    int gph = threadIdx.x;
    float c = fmaxf(counts[gph], 1.0f);
    float s = 0.0f;
    for (int f = 0; f < 128; ++f) s += pooled[gph * 128 + f] * w_out[f];
    out[gph] = s / c + b_out[0];
}

extern "C" void kernel_launch(void* const* d_in, const int* in_sizes, int n_in,
                              void* d_out, int out_size, void* d_ws, size_t ws_size,
                              hipStream_t stream) {
    const float* x     = (const float*)d_in[0];
    const int*   edge  = (const int*)d_in[1];   // [2, E]
    const int*   batch = (const int*)d_in[2];
    const float* w1    = (const float*)d_in[3];
    const float* b1    = (const float*)d_in[4];
    const float* w2    = (const float*)d_in[5];
    const float* b2    = (const float*)d_in[6];
    const float* w_out = (const float*)d_in[7];
    const float* b_out = (const float*)d_in[8];
    float* out = (float*)d_out;

    char* ws = (char*)d_ws;
    size_t off = 0;
    auto alloc = [&](size_t bytes) {
        void* p = ws + off;
        off += (bytes + 511) & ~(size_t)511;
        return p;
    };
    const size_t FEAT_BYTES = (size_t)N_NODES * 128 * 4;     // 51.2 MB
    __half*   ht16       = (__half*)alloc(FEAT_BYTES / 2);   // 25.6 MB
    float*    buf1       = (float*)alloc(FEAT_BYTES);        // Y (aliases pairbuf)
    unsigned* pairbuf    = (unsigned*)buf1;                  // 8.0 MB, dead before first gather
    float*    dinv       = (float*)alloc(N_NODES * 4);
    int*      row_off    = (int*)alloc(N_NODES * 4);
    int*      csr_src    = (int*)alloc(N_EDGES * 4);         // 6.4 MB
    int*      bucket_cur = (int*)alloc((NB + 1) * 4);
    int*      bucket_off = (int*)alloc((NB + 1) * 4);
    float*    pooled     = (float*)alloc(N_GRAPHS * 128 * 4);
    float*    counts     = (float*)alloc(N_GRAPHS * 4);

    const int* src = edge;
    const int* dst = edge + N_EDGES;

    hipMemsetAsync(bucket_cur, 0, (NB + 1) * 4, stream);
    hipMemsetAsync(pooled, 0, N_GRAPHS * 128 * 4, stream);
    hipMemsetAsync(counts, 0, N_GRAPHS * 4, stream);

    // ----- bucketed CSR build (no per-edge global atomics) -----
    stage_kernel<<<SBLOCKS, 256, 0, stream>>>(src, dst, bucket_cur, pairbuf);
    scan_buckets_kernel<<<1, 256, 0, stream>>>(bucket_cur, bucket_off);
    localsort_kernel<<<NB, 256, 0, stream>>>(pairbuf, bucket_cur, bucket_off,
                                             csr_src, row_off, dinv);

    // ----- layer 1 -----
    int gblocks = (N_NODES + BM - 1) / BM;
    gemm_kernel<<<gblocks, 256, 0, stream>>>(x, w1, dinv, ht16);
    gather_kernel<<<(N_NODES * 32 + 255) / 256, 256, 0, stream>>>(row_off, csr_src, ht16, dinv, b1, buf1);

    // ----- layer 2 -----
    gemm_kernel<<<gblocks, 256, 0, stream>>>(buf1, w2, dinv, ht16);
    gather_kernel<<<(N_NODES * 32 + 255) / 256, 256, 0, stream>>>(row_off, csr_src, ht16, dinv, b2, buf1);

    // ----- pool + head -----
    int ngroups = (N_NODES + NODES_PER_GROUP - 1) / NODES_PER_GROUP;
    pool_kernel<<<(ngroups * 32 + 255) / 256, 256, 0, stream>>>(buf1, batch, pooled, counts);
    out_kernel<<<1, 256, 0, stream>>>(pooled, counts, w_out, b_out, out);
}

// Round 8
// 351.830 us; speedup vs baseline: 3.9482x; 1.2146x over previous
//
#include <hip/hip_runtime.h>
#include <hip/hip_fp16.h>

#define N_NODES 100000
#define N_EDGES 1600000
#define N_GRAPHS 256
#define NB 1563              // ceil(100000 / 64) buckets of 64 nodes
#define BCAP 1280            // per-bucket fixed capacity (mean 1024, +8 sigma)
#define SBLOCKS 128          // stage blocks; 12500 edges each

// ---------------- stage: two-pass LDS-cursor bucket scatter -----------------
__global__ __launch_bounds__(256) void stage_kernel(const int* __restrict__ src,
                                                    const int* __restrict__ dst,
                                                    int* __restrict__ bucket_cur,
                                                    unsigned* __restrict__ pairbuf) {
    __shared__ int lcnt[NB];
    __shared__ int lcur[NB];
    const int tid = threadIdx.x;
    const int per = (N_EDGES + SBLOCKS - 1) / SBLOCKS;   // 12500
    const int e0 = blockIdx.x * per;
    const int e1 = min(e0 + per, N_EDGES);

    for (int i = tid; i < NB; i += 256) lcnt[i] = 0;
    __syncthreads();
    for (int e = e0 + tid; e < e1; e += 256)
        atomicAdd(&lcnt[dst[e] >> 6], 1);
    __syncthreads();
    for (int i = tid; i < NB; i += 256) {
        int c = lcnt[i];
        lcur[i] = c ? atomicAdd(&bucket_cur[i], c) : 0;   // reserve [base, base+c)
    }
    __syncthreads();
    for (int e = e0 + tid; e < e1; e += 256) {
        int d = dst[e];
        int b = d >> 6;
        int p = atomicAdd(&lcur[b], 1);                   // LDS cursor
        if (p < BCAP)
            pairbuf[(size_t)b * BCAP + p] =
                ((unsigned)(d & 63) << 17) | (unsigned)src[e];
    }
}

// ---------------- scan over bucket totals -> bucket_off ---------------------
#define BVPT 7   // 256*7 = 1792 >= NB
__global__ __launch_bounds__(256) void scan_buckets_kernel(const int* __restrict__ bucket_cur,
                                                           int* __restrict__ bucket_off) {
    __shared__ int tsum[256];
    int tid = threadIdx.x;
    int v[BVPT];
    int s = 0;
#pragma unroll
    for (int j = 0; j < BVPT; ++j) {
        int idx = tid * BVPT + j;
        v[j] = (idx < NB) ? min(bucket_cur[idx], BCAP) : 0;
        s += v[j];
    }
    tsum[tid] = s;
    __syncthreads();
    for (int off = 1; off < 256; off <<= 1) {
        int y = (tid >= off) ? tsum[tid - off] : 0;
        __syncthreads();
        tsum[tid] += y;
        __syncthreads();
    }
    int run = (tid > 0) ? tsum[tid - 1] : 0;
#pragma unroll
    for (int j = 0; j < BVPT; ++j) {
        int idx = tid * BVPT + j;
        if (idx < NB) bucket_off[idx] = run;
        run += v[j];
    }
    if (tid == 255) bucket_off[NB] = tsum[255];
}

// ---------------- per-bucket counting sort -> csr/row_off/dinv --------------
__global__ __launch_bounds__(256) void localsort_kernel(const unsigned* __restrict__ pairbuf,
                                                        const int* __restrict__ bucket_cur,
                                                        const int* __restrict__ bucket_off,
                                                        int* __restrict__ csr_src,
                                                        int* __restrict__ row_off,
                                                        float* __restrict__ dinv) {
    __shared__ int ldeg[64];
    __shared__ int loff[64];
    __shared__ int lcur[64];
    int tid = threadIdx.x;
    int b = blockIdx.x;
    int cnt = min(bucket_cur[b], BCAP);
    int base = bucket_off[b];
    const unsigned* pb = pairbuf + (size_t)b * BCAP;
    int n0 = b << 6;

    if (tid < 64) ldeg[tid] = 0;
    __syncthreads();
    for (int i = tid; i < cnt; i += 256)
        atomicAdd(&ldeg[pb[i] >> 17], 1);
    __syncthreads();
    if (tid < 64) loff[tid] = ldeg[tid];
    __syncthreads();
    for (int off = 1; off < 64; off <<= 1) {
        int y = 0;
        if (tid < 64 && tid >= off) y = loff[tid - off];
        __syncthreads();
        if (tid < 64) loff[tid] += y;
        __syncthreads();
    }
    if (tid < 64) {
        int ex = loff[tid] - ldeg[tid];   // exclusive prefix
        lcur[tid] = ex;
        int n = n0 + tid;
        if (n < N_NODES) {
            row_off[n] = base + ex;
            dinv[n] = rsqrtf((float)ldeg[tid] + 1.0f);
        }
    }
    __syncthreads();
    for (int i = tid; i < cnt; i += 256) {
        unsigned w = pb[i];
        int dl = w >> 17;
        int s = (int)(w & 0x1FFFFu);
        int p = atomicAdd(&lcur[dl], 1);
        csr_src[base + p] = s;
    }
}

// ---------------- GEMM (fp32 X): HT16 = fp16((X @ W) * dinv[row]) -----------
#define BM 128
#define KC 32
__device__ __forceinline__ unsigned pack2(float a, float b) {
    __half2 h = __floats2half2_rn(a, b);
    return *reinterpret_cast<unsigned*>(&h);
}
__global__ __launch_bounds__(256) void gemm_kernel(const float* __restrict__ X,
                                                   const float* __restrict__ W,
                                                   const float* __restrict__ dinv,
                                                   __half* __restrict__ HT) {
    __shared__ float Xt[KC][132];
    __shared__ float Wl[KC][128];
    const int tid = threadIdx.x;
    const int row0 = blockIdx.x * BM;
    const int cg = tid & 15;
    const int rg = tid >> 4;
    const int c_lo = cg * 4, r_lo = rg * 4;

    float acc[8][8];
#pragma unroll
    for (int i = 0; i < 8; ++i)
#pragma unroll
        for (int j = 0; j < 8; ++j) acc[i][j] = 0.0f;

    for (int kb = 0; kb < 128; kb += KC) {
        __syncthreads();
#pragma unroll
        for (int i = 0; i < 4; ++i) {
            int idx = tid * 4 + i * 1024;        // 0..4095
            int r = idx >> 5;
            int kk = idx & 31;
            int rr = row0 + r;
            if (rr >= N_NODES) rr = N_NODES - 1;
            const float4 v = *(const float4*)&X[(size_t)rr * 128 + kb + kk];
            Xt[kk + 0][r] = v.x;
            Xt[kk + 1][r] = v.y;
            Xt[kk + 2][r] = v.z;
            Xt[kk + 3][r] = v.w;
        }
#pragma unroll
        for (int i = 0; i < 4; ++i) {
            int idx = tid * 4 + i * 1024;
            int r = idx >> 7;
            int c = idx & 127;
            *(float4*)&Wl[r][c] = *(const float4*)&W[(size_t)(kb + r) * 128 + c];
        }
        __syncthreads();
#pragma unroll 4
        for (int k = 0; k < KC; ++k) {
            float4 a0 = *(float4*)&Xt[k][r_lo];
            float4 a1 = *(float4*)&Xt[k][64 + r_lo];
            float4 b0 = *(float4*)&Wl[k][c_lo];
            float4 b1 = *(float4*)&Wl[k][64 + c_lo];
            float a[8] = {a0.x, a0.y, a0.z, a0.w, a1.x, a1.y, a1.z, a1.w};
            float b[8] = {b0.x, b0.y, b0.z, b0.w, b1.x, b1.y, b1.z, b1.w};
#pragma unroll
            for (int i = 0; i < 8; ++i)
#pragma unroll
                for (int j = 0; j < 8; ++j)
                    acc[i][j] = fmaf(a[i], b[j], acc[i][j]);
        }
    }
#pragma unroll
    for (int i = 0; i < 8; ++i) {
        int ri = (i < 4) ? (r_lo + i) : (64 + r_lo + i - 4);
        int rr = row0 + ri;
        if (rr < N_NODES) {
            float di = dinv[rr];
            uint2 o0, o1;
            o0.x = pack2(acc[i][0] * di, acc[i][1] * di);
            o0.y = pack2(acc[i][2] * di, acc[i][3] * di);
            o1.x = pack2(acc[i][4] * di, acc[i][5] * di);
            o1.y = pack2(acc[i][6] * di, acc[i][7] * di);
            *(uint2*)&HT[(size_t)rr * 128 + c_lo] = o0;
            *(uint2*)&HT[(size_t)rr * 128 + 64 + c_lo] = o1;
        }
    }
}

// ---------------- GEMM (fp16 X): HT16 = fp16((X @ W) * dinv[row]) -----------
__global__ __launch_bounds__(256) void gemm16_kernel(const __half* __restrict__ X,
                                                     const float* __restrict__ W,
                                                     const float* __restrict__ dinv,
                                                     __half* __restrict__ HT) {
    __shared__ float Xt[KC][132];
    __shared__ float Wl[KC][128];
    const int tid = threadIdx.x;
    const int row0 = blockIdx.x * BM;
    const int cg = tid & 15;
    const int rg = tid >> 4;
    const int c_lo = cg * 4, r_lo = rg * 4;

    float acc[8][8];
#pragma unroll
    for (int i = 0; i < 8; ++i)
#pragma unroll
        for (int j = 0; j < 8; ++j) acc[i][j] = 0.0f;

    for (int kb = 0; kb < 128; kb += KC) {
        __syncthreads();
#pragma unroll
        for (int i = 0; i < 4; ++i) {
            int idx = tid * 4 + i * 1024;        // 0..4095
            int r = idx >> 5;
            int kk = idx & 31;
            int rr = row0 + r;
            if (rr >= N_NODES) rr = N_NODES - 1;
            uint2 w = *(const uint2*)&X[(size_t)rr * 128 + kb + kk];
            float2 p0 = __half22float2(*reinterpret_cast<__half2*>(&w.x));
            float2 p1 = __half22float2(*reinterpret_cast<__half2*>(&w.y));
            Xt[kk + 0][r] = p0.x;
            Xt[kk + 1][r] = p0.y;
            Xt[kk + 2][r] = p1.x;
            Xt[kk + 3][r] = p1.y;
        }
#pragma unroll
        for (int i = 0; i < 4; ++i) {
            int idx = tid * 4 + i * 1024;
            int r = idx >> 7;
            int c = idx & 127;
            *(float4*)&Wl[r][c] = *(const float4*)&W[(size_t)(kb + r) * 128 + c];
        }
        __syncthreads();
#pragma unroll 4
        for (int k = 0; k < KC; ++k) {
            float4 a0 = *(float4*)&Xt[k][r_lo];
            float4 a1 = *(float4*)&Xt[k][64 + r_lo];
            float4 b0 = *(float4*)&Wl[k][c_lo];
            float4 b1 = *(float4*)&Wl[k][64 + c_lo];
            float a[8] = {a0.x, a0.y, a0.z, a0.w, a1.x, a1.y, a1.z, a1.w};
            float b[8] = {b0.x, b0.y, b0.z, b0.w, b1.x, b1.y, b1.z, b1.w};
#pragma unroll
            for (int i = 0; i < 8; ++i)
#pragma unroll
                for (int j = 0; j < 8; ++j)
                    acc[i][j] = fmaf(a[i], b[j], acc[i][j]);
        }
    }
#pragma unroll
    for (int i = 0; i < 8; ++i) {
        int ri = (i < 4) ? (r_lo + i) : (64 + r_lo + i - 4);
        int rr = row0 + ri;
        if (rr < N_NODES) {
            float di = dinv[rr];
            uint2 o0, o1;
            o0.x = pack2(acc[i][0] * di, acc[i][1] * di);
            o0.y = pack2(acc[i][2] * di, acc[i][3] * di);
            o1.x = pack2(acc[i][4] * di, acc[i][5] * di);
            o1.y = pack2(acc[i][6] * di, acc[i][7] * di);
            *(uint2*)&HT[(size_t)rr * 128 + c_lo] = o0;
            *(uint2*)&HT[(size_t)rr * 128 + 64 + c_lo] = o1;
        }
    }
}

// ---------------- gather: Y16[n] = relu(dinv[n]*(sum ht16[src]+ht16[n])+b) --
// 16 lanes/node, 16B per lane (8 fp16 features), unroll-4 with independent
// accumulator sets -> 4 outstanding 16B loads per lane (8x bytes-in-flight
// vs R7's 1x8B). fp32 accumulation throughout.
__device__ __forceinline__ void add8(float* a, uint4 w) {
    float2 p0 = __half22float2(*reinterpret_cast<__half2*>(&w.x));
    float2 p1 = __half22float2(*reinterpret_cast<__half2*>(&w.y));
    float2 p2 = __half22float2(*reinterpret_cast<__half2*>(&w.z));
    float2 p3 = __half22float2(*reinterpret_cast<__half2*>(&w.w));
    a[0] += p0.x; a[1] += p0.y; a[2] += p1.x; a[3] += p1.y;
    a[4] += p2.x; a[5] += p2.y; a[6] += p3.x; a[7] += p3.y;
}
__global__ __launch_bounds__(256) void gather_kernel(const int* __restrict__ row_off,
                                                     const int* __restrict__ csr_src,
                                                     const __half* __restrict__ ht,
                                                     const float* __restrict__ dinv,
                                                     const float* __restrict__ b,
                                                     __half* __restrict__ Y) {
    int t = blockIdx.x * 256 + threadIdx.x;
    int n = t >> 4;
    if (n >= N_NODES) return;
    int f = (t & 15) * 8;
    int e0 = row_off[n];
    int e1 = (n < N_NODES - 1) ? row_off[n + 1] : N_EDGES;
    const __half* htf = ht + f;

    float a0[8] = {0,0,0,0,0,0,0,0};
    float a1[8] = {0,0,0,0,0,0,0,0};
    float a2[8] = {0,0,0,0,0,0,0,0};
    float a3[8] = {0,0,0,0,0,0,0,0};
    add8(a0, *(const uint4*)&htf[(size_t)n * 128]);   // self-loop term

    int e = e0;
    for (; e + 4 <= e1; e += 4) {
        int s0 = csr_src[e], s1 = csr_src[e + 1];
        int s2 = csr_src[e + 2], s3 = csr_src[e + 3];
        uint4 w0 = *(const uint4*)&htf[(size_t)s0 * 128];
        uint4 w1 = *(const uint4*)&htf[(size_t)s1 * 128];
        uint4 w2 = *(const uint4*)&htf[(size_t)s2 * 128];
        uint4 w3 = *(const uint4*)&htf[(size_t)s3 * 128];
        add8(a0, w0); add8(a1, w1); add8(a2, w2); add8(a3, w3);
    }
    for (; e < e1; ++e)
        add8(a0, *(const uint4*)&htf[(size_t)csr_src[e] * 128]);

    float di = dinv[n];
    float4 bb0 = *(const float4*)&b[f];
    float4 bb1 = *(const float4*)&b[f + 4];
    float r0 = fmaxf((a0[0]+a1[0]+a2[0]+a3[0]) * di + bb0.x, 0.0f);
    float r1 = fmaxf((a0[1]+a1[1]+a2[1]+a3[1]) * di + bb0.y, 0.0f);
    float r2 = fmaxf((a0[2]+a1[2]+a2[2]+a3[2]) * di + bb0.z, 0.0f);
    float r3 = fmaxf((a0[3]+a1[3]+a2[3]+a3[3]) * di + bb0.w, 0.0f);
    float r4 = fmaxf((a0[4]+a1[4]+a2[4]+a3[4]) * di + bb1.x, 0.0f);
    float r5 = fmaxf((a0[5]+a1[5]+a2[5]+a3[5]) * di + bb1.y, 0.0f);
    float r6 = fmaxf((a0[6]+a1[6]+a2[6]+a3[6]) * di + bb1.z, 0.0f);
    float r7 = fmaxf((a0[7]+a1[7]+a2[7]+a3[7]) * di + bb1.w, 0.0f);
    uint4 o;
    o.x = pack2(r0, r1);
    o.y = pack2(r2, r3);
    o.z = pack2(r4, r5);
    o.w = pack2(r6, r7);
    *(uint4*)&Y[(size_t)n * 128 + f] = o;
}

// ---------------- mean-pool (fp16 Y): run-length over sorted batch ----------
#define NODES_PER_GROUP 100
__global__ __launch_bounds__(256) void pool_kernel(const __half* __restrict__ Y,
                                                   const int* __restrict__ batch,
                                                   float* __restrict__ pooled,
                                                   float* __restrict__ counts) {
    int g = (blockIdx.x * 256 + threadIdx.x) >> 5;
    int lane = threadIdx.x & 31;
    int f = lane * 4;
    int n0 = g * NODES_PER_GROUP;
    if (n0 >= N_NODES) return;
    int n1 = min(n0 + NODES_PER_GROUP, N_NODES);
    int cur = batch[n0];
    float4 acc = make_float4(0, 0, 0, 0);
    float cnt = 0.0f;
    for (int n = n0; n < n1; ++n) {
        int bid = batch[n];
        if (bid != cur) {
            float* p = &pooled[cur * 128 + f];
            atomicAdd(p + 0, acc.x); atomicAdd(p + 1, acc.y);
            atomicAdd(p + 2, acc.z); atomicAdd(p + 3, acc.w);
            if (lane == 0) atomicAdd(&counts[cur], cnt);
            acc = make_float4(0, 0, 0, 0); cnt = 0.0f; cur = bid;
        }
        uint2 w = *(const uint2*)&Y[(size_t)n * 128 + f];
        float2 p0 = __half22float2(*reinterpret_cast<__half2*>(&w.x));
        float2 p1 = __half22float2(*reinterpret_cast<__half2*>(&w.y));
        acc.x += p0.x; acc.y += p0.y; acc.z += p1.x; acc.w += p1.y;
        cnt += 1.0f;
    }
    float* p = &pooled[cur * 128 + f];
    atomicAdd(p + 0, acc.x); atomicAdd(p + 1, acc.y);
    atomicAdd(p + 2, acc.z); atomicAdd(p + 3, acc.w);
    if (lane == 0) atomicAdd(&counts[cur], cnt);
}

// ---------------- head: out[g] = dot(pooled[g], w_out)/count + b_out --------
__global__ __launch_bounds__(256) void out_kernel(const float* __restrict__ pooled,
                                                  const float* __restrict__ counts,
                                                  const float* __restrict__ w_out,
                                                  const float* __restrict__ b_out,
                                                  float* __restrict__ out) {
    int gph = threadIdx.x;
    float c = fmaxf(counts[gph], 1.0f);
    float s = 0.0f;
    for (int f = 0; f < 128; ++f) s += pooled[gph * 128 + f] * w_out[f];
    out[gph] = s / c + b_out[0];
}

extern "C" void kernel_launch(void* const* d_in, const int* in_sizes, int n_in,
                              void* d_out, int out_size, void* d_ws, size_t ws_size,
                              hipStream_t stream) {
    const float* x     = (const float*)d_in[0];
    const int*   edge  = (const int*)d_in[1];   // [2, E]
    const int*   batch = (const int*)d_in[2];
    const float* w1    = (const float*)d_in[3];
    const float* b1    = (const float*)d_in[4];
    const float* w2    = (const float*)d_in[5];
    const float* b2    = (const float*)d_in[6];
    const float* w_out = (const float*)d_in[7];
    const float* b_out = (const float*)d_in[8];
    float* out = (float*)d_out;

    char* ws = (char*)d_ws;
    size_t off = 0;
    auto alloc = [&](size_t bytes) {
        void* p = ws + off;
        off += (bytes + 511) & ~(size_t)511;
        return p;
    };
    const size_t FEAT_BYTES = (size_t)N_NODES * 128 * 4;     // 51.2 MB
    __half*   ht16       = (__half*)alloc(FEAT_BYTES / 2);   // 25.6 MB
    __half*   y16        = (__half*)alloc(FEAT_BYTES / 2);   // 25.6 MB (aliases pairbuf)
    unsigned* pairbuf    = (unsigned*)y16;                   // 8.0 MB, dead before first gather
    float*    dinv       = (float*)alloc(N_NODES * 4);
    int*      row_off    = (int*)alloc(N_NODES * 4);
    int*      csr_src    = (int*)alloc(N_EDGES * 4);         // 6.4 MB
    int*      bucket_cur = (int*)alloc((NB + 1) * 4);
    int*      bucket_off = (int*)alloc((NB + 1) * 4);
    float*    pooled     = (float*)alloc(N_GRAPHS * 128 * 4);
    float*    counts     = (float*)alloc(N_GRAPHS * 4);

    const int* src = edge;
    const int* dst = edge + N_EDGES;

    hipMemsetAsync(bucket_cur, 0, (NB + 1) * 4, stream);
    hipMemsetAsync(pooled, 0, N_GRAPHS * 128 * 4, stream);
    hipMemsetAsync(counts, 0, N_GRAPHS * 4, stream);

    // ----- bucketed CSR build (no per-edge global atomics) -----
    stage_kernel<<<SBLOCKS, 256, 0, stream>>>(src, dst, bucket_cur, pairbuf);
    scan_buckets_kernel<<<1, 256, 0, stream>>>(bucket_cur, bucket_off);
    localsort_kernel<<<NB, 256, 0, stream>>>(pairbuf, bucket_cur, bucket_off,
                                             csr_src, row_off, dinv);

    // ----- layer 1 -----
    int gblocks = (N_NODES + BM - 1) / BM;
    gemm_kernel<<<gblocks, 256, 0, stream>>>(x, w1, dinv, ht16);
    gather_kernel<<<(N_NODES * 16 + 255) / 256, 256, 0, stream>>>(row_off, csr_src, ht16, dinv, b1, y16);

    // ----- layer 2 -----
    gemm16_kernel<<<gblocks, 256, 0, stream>>>(y16, w2, dinv, ht16);
    gather_kernel<<<(N_NODES * 16 + 255) / 256, 256, 0, stream>>>(row_off, csr_src, ht16, dinv, b2, y16);

    // ----- pool + head -----
    int ngroups = (N_NODES + NODES_PER_GROUP - 1) / NODES_PER_GROUP;
    pool_kernel<<<(ngroups * 32 + 255) / 256, 256, 0, stream>>>(y16, batch, pooled, counts);
    out_kernel<<<1, 256, 0, stream>>>(pooled, counts, w_out, b_out, out);
}

// Round 9
// 263.399 us; speedup vs baseline: 5.2738x; 1.3357x over previous
//
#include <hip/hip_runtime.h>
#include <hip/hip_fp16.h>

#define N_NODES 100000
#define N_EDGES 1600000
#define N_GRAPHS 256
#define NB 1563              // ceil(100000 / 64) buckets of 64 nodes
#define BCAP 1280            // per-bucket fixed capacity (mean 1024, +8 sigma)
#define SBLOCKS 128          // stage blocks; 12500 edges each (1024 thr)

typedef _Float16 half8 __attribute__((ext_vector_type(8)));
typedef float f32x4 __attribute__((ext_vector_type(4)));

__device__ __forceinline__ unsigned pack2(float a, float b) {
    __half2 h = __floats2half2_rn(a, b);
    return *reinterpret_cast<unsigned*>(&h);
}

// ---------------- stage: two-pass LDS-cursor bucket scatter -----------------
// 1024 threads: 4x waves vs R8 -> serial per-wave iteration depth /4
// (was latency-bound at 4.9% occupancy). Reservation depth still 128.
__global__ __launch_bounds__(1024) void stage_kernel(const int* __restrict__ src,
                                                     const int* __restrict__ dst,
                                                     int* __restrict__ bucket_cur,
                                                     unsigned* __restrict__ pairbuf) {
    __shared__ int lcnt[NB];
    __shared__ int lcur[NB];
    const int tid = threadIdx.x;
    const int per = (N_EDGES + SBLOCKS - 1) / SBLOCKS;   // 12500
    const int e0 = blockIdx.x * per;
    const int e1 = min(e0 + per, N_EDGES);

    for (int i = tid; i < NB; i += 1024) lcnt[i] = 0;
    __syncthreads();
    for (int e = e0 + tid; e < e1; e += 1024)
        atomicAdd(&lcnt[dst[e] >> 6], 1);
    __syncthreads();
    for (int i = tid; i < NB; i += 1024) {
        int c = lcnt[i];
        lcur[i] = c ? atomicAdd(&bucket_cur[i], c) : 0;   // reserve [base, base+c)
    }
    __syncthreads();
    for (int e = e0 + tid; e < e1; e += 1024) {
        int d = dst[e];
        int b = d >> 6;
        int p = atomicAdd(&lcur[b], 1);                   // LDS cursor
        if (p < BCAP)
            pairbuf[(size_t)b * BCAP + p] =
                ((unsigned)(d & 63) << 17) | (unsigned)src[e];
    }
}

// ---------------- scan over bucket totals -> bucket_off ---------------------
#define BVPT 7   // 256*7 = 1792 >= NB
__global__ __launch_bounds__(256) void scan_buckets_kernel(const int* __restrict__ bucket_cur,
                                                           int* __restrict__ bucket_off) {
    __shared__ int tsum[256];
    int tid = threadIdx.x;
    int v[BVPT];
    int s = 0;
#pragma unroll
    for (int j = 0; j < BVPT; ++j) {
        int idx = tid * BVPT + j;
        v[j] = (idx < NB) ? min(bucket_cur[idx], BCAP) : 0;
        s += v[j];
    }
    tsum[tid] = s;
    __syncthreads();
    for (int off = 1; off < 256; off <<= 1) {
        int y = (tid >= off) ? tsum[tid - off] : 0;
        __syncthreads();
        tsum[tid] += y;
        __syncthreads();
    }
    int run = (tid > 0) ? tsum[tid - 1] : 0;
#pragma unroll
    for (int j = 0; j < BVPT; ++j) {
        int idx = tid * BVPT + j;
        if (idx < NB) bucket_off[idx] = run;
        run += v[j];
    }
    if (tid == 255) bucket_off[NB] = tsum[255];
}

// ---------------- per-bucket counting sort -> csr/row_off/dinv --------------
__global__ __launch_bounds__(256) void localsort_kernel(const unsigned* __restrict__ pairbuf,
                                                        const int* __restrict__ bucket_cur,
                                                        const int* __restrict__ bucket_off,
                                                        int* __restrict__ csr_src,
                                                        int* __restrict__ row_off,
                                                        float* __restrict__ dinv) {
    __shared__ int ldeg[64];
    __shared__ int loff[64];
    __shared__ int lcur[64];
    int tid = threadIdx.x;
    int b = blockIdx.x;
    int cnt = min(bucket_cur[b], BCAP);
    int base = bucket_off[b];
    const unsigned* pb = pairbuf + (size_t)b * BCAP;
    int n0 = b << 6;

    if (tid < 64) ldeg[tid] = 0;
    __syncthreads();
    for (int i = tid; i < cnt; i += 256)
        atomicAdd(&ldeg[pb[i] >> 17], 1);
    __syncthreads();
    if (tid < 64) loff[tid] = ldeg[tid];
    __syncthreads();
    for (int off = 1; off < 64; off <<= 1) {
        int y = 0;
        if (tid < 64 && tid >= off) y = loff[tid - off];
        __syncthreads();
        if (tid < 64) loff[tid] += y;
        __syncthreads();
    }
    if (tid < 64) {
        int ex = loff[tid] - ldeg[tid];   // exclusive prefix
        lcur[tid] = ex;
        int n = n0 + tid;
        if (n < N_NODES) {
            row_off[n] = base + ex;
            dinv[n] = rsqrtf((float)ldeg[tid] + 1.0f);
        }
    }
    __syncthreads();
    for (int i = tid; i < cnt; i += 256) {
        unsigned w = pb[i];
        int dl = w >> 17;
        int s = (int)(w & 0x1FFFFu);
        int p = atomicAdd(&lcur[dl], 1);
        csr_src[base + p] = s;
    }
}

// ---------------- W prep: Wt16[n][k] = fp16(W[k][n]) ------------------------
__global__ __launch_bounds__(256) void wprep_kernel(const float* __restrict__ W,
                                                    __half* __restrict__ Wt) {
    int t = blockIdx.x * 256 + threadIdx.x;   // 16384
    int n = t >> 7, k = t & 127;
    Wt[t] = (__half)W[k * 128 + n];
}

// ---------------- MFMA GEMM: HT16[N,128] = fp16((X @ W) * dinv[row]) --------
// 128 rows/block, 4 waves; wave w owns rows [w*32, w*32+32).
// mfma_f32_16x16x32_f16: A lane layout row=lane&15, k=(lane>>4)*8+j;
// B lane layout col=lane&15, k=(lane>>4)*8+j (Wt[n][k] gives contiguous 16B);
// C/D: col=lane&15, row=(lane>>4)*4+reg  [HW-verified, guide s3].
// LDS rows padded to 136 halves (272B): b128 frag reads are <=2-way aliased.
__global__ __launch_bounds__(256) void gemm_mfma_kernel(const float* __restrict__ Xf,
                                                        const __half* __restrict__ Xh,
                                                        const __half* __restrict__ Wt,
                                                        const float* __restrict__ dinv,
                                                        __half* __restrict__ HT,
                                                        int xf16) {
    __shared__ __half Xl[128][136];
    __shared__ __half Wl[128][136];
    const int tid = threadIdx.x;
    const int row0 = blockIdx.x * 128;

    // stage Wt (16384 halves, uint4 = 8 halves)
#pragma unroll
    for (int i = 0; i < 8; ++i) {
        int idx = tid + i * 256;              // 0..2047
        int n = idx >> 4, c0 = (idx & 15) * 8;
        *(uint4*)&Wl[n][c0] = *(const uint4*)&Wt[n * 128 + c0];
    }
    // stage X tile -> fp16
    if (xf16) {
#pragma unroll
        for (int i = 0; i < 8; ++i) {
            int idx = tid + i * 256;
            int r = idx >> 4, c0 = (idx & 15) * 8;
            int rr = min(row0 + r, N_NODES - 1);
            *(uint4*)&Xl[r][c0] = *(const uint4*)&Xh[(size_t)rr * 128 + c0];
        }
    } else {
#pragma unroll
        for (int i = 0; i < 16; ++i) {
            int idx = tid + i * 256;          // 0..4095
            int r = idx >> 5, c0 = (idx & 31) * 4;
            int rr = min(row0 + r, N_NODES - 1);
            float4 v = *(const float4*)&Xf[(size_t)rr * 128 + c0];
            uint2 o;
            o.x = pack2(v.x, v.y);
            o.y = pack2(v.z, v.w);
            *(uint2*)&Xl[r][c0] = o;
        }
    }
    __syncthreads();

    const int wv = tid >> 6;
    const int lane = tid & 63;
    const int lr = lane & 15;      // row-in-tile (A) / col-in-tile (B,D)
    const int lg = lane >> 4;      // k-octet group / D row group

    f32x4 acc[2][8];
#pragma unroll
    for (int mt = 0; mt < 2; ++mt)
#pragma unroll
        for (int nt = 0; nt < 8; ++nt) acc[mt][nt] = (f32x4){0.f, 0.f, 0.f, 0.f};

#pragma unroll
    for (int ks = 0; ks < 4; ++ks) {
        const int kb = ks * 32 + lg * 8;
        half8 a0 = *reinterpret_cast<const half8*>(&Xl[wv * 32 + lr][kb]);
        half8 a1 = *reinterpret_cast<const half8*>(&Xl[wv * 32 + 16 + lr][kb]);
        half8 b[8];
#pragma unroll
        for (int nt = 0; nt < 8; ++nt)
            b[nt] = *reinterpret_cast<const half8*>(&Wl[nt * 16 + lr][kb]);
#pragma unroll
        for (int nt = 0; nt < 8; ++nt) {
            acc[0][nt] = __builtin_amdgcn_mfma_f32_16x16x32_f16(a0, b[nt], acc[0][nt], 0, 0, 0);
            acc[1][nt] = __builtin_amdgcn_mfma_f32_16x16x32_f16(a1, b[nt], acc[1][nt], 0, 0, 0);
        }
    }

    // epilogue: D[row=(lg*4+i), col=lr] per tile; scale dinv, store fp16
#pragma unroll
    for (int mt = 0; mt < 2; ++mt) {
#pragma unroll
        for (int i = 0; i < 4; ++i) {
            int rr = row0 + wv * 32 + mt * 16 + lg * 4 + i;
            if (rr < N_NODES) {
                float di = dinv[rr];
#pragma unroll
                for (int nt = 0; nt < 8; ++nt)
                    HT[(size_t)rr * 128 + nt * 16 + lr] = (__half)(acc[mt][nt][i] * di);
            }
        }
    }
}

// ---------------- gather: Y16[n] = relu(dinv[n]*(sum ht16[src]+ht16[n])+b) --
__device__ __forceinline__ void add8(float* a, uint4 w) {
    float2 p0 = __half22float2(*reinterpret_cast<__half2*>(&w.x));
    float2 p1 = __half22float2(*reinterpret_cast<__half2*>(&w.y));
    float2 p2 = __half22float2(*reinterpret_cast<__half2*>(&w.z));
    float2 p3 = __half22float2(*reinterpret_cast<__half2*>(&w.w));
    a[0] += p0.x; a[1] += p0.y; a[2] += p1.x; a[3] += p1.y;
    a[4] += p2.x; a[5] += p2.y; a[6] += p3.x; a[7] += p3.y;
}
__global__ __launch_bounds__(256) void gather_kernel(const int* __restrict__ row_off,
                                                     const int* __restrict__ csr_src,
                                                     const __half* __restrict__ ht,
                                                     const float* __restrict__ dinv,
                                                     const float* __restrict__ b,
                                                     __half* __restrict__ Y) {
    int t = blockIdx.x * 256 + threadIdx.x;
    int n = t >> 4;
    if (n >= N_NODES) return;
    int f = (t & 15) * 8;
    int e0 = row_off[n];
    int e1 = (n < N_NODES - 1) ? row_off[n + 1] : N_EDGES;
    const __half* htf = ht + f;

    float a0[8] = {0,0,0,0,0,0,0,0};
    float a1[8] = {0,0,0,0,0,0,0,0};
    float a2[8] = {0,0,0,0,0,0,0,0};
    float a3[8] = {0,0,0,0,0,0,0,0};
    add8(a0, *(const uint4*)&htf[(size_t)n * 128]);   // self-loop term

    int e = e0;
    for (; e + 4 <= e1; e += 4) {
        int s0 = csr_src[e], s1 = csr_src[e + 1];
        int s2 = csr_src[e + 2], s3 = csr_src[e + 3];
        uint4 w0 = *(const uint4*)&htf[(size_t)s0 * 128];
        uint4 w1 = *(const uint4*)&htf[(size_t)s1 * 128];
        uint4 w2 = *(const uint4*)&htf[(size_t)s2 * 128];
        uint4 w3 = *(const uint4*)&htf[(size_t)s3 * 128];
        add8(a0, w0); add8(a1, w1); add8(a2, w2); add8(a3, w3);
    }
    for (; e < e1; ++e)
        add8(a0, *(const uint4*)&htf[(size_t)csr_src[e] * 128]);

    float di = dinv[n];
    float4 bb0 = *(const float4*)&b[f];
    float4 bb1 = *(const float4*)&b[f + 4];
    float r0 = fmaxf((a0[0]+a1[0]+a2[0]+a3[0]) * di + bb0.x, 0.0f);
    float r1 = fmaxf((a0[1]+a1[1]+a2[1]+a3[1]) * di + bb0.y, 0.0f);
    float r2 = fmaxf((a0[2]+a1[2]+a2[2]+a3[2]) * di + bb0.z, 0.0f);
    float r3 = fmaxf((a0[3]+a1[3]+a2[3]+a3[3]) * di + bb0.w, 0.0f);
    float r4 = fmaxf((a0[4]+a1[4]+a2[4]+a3[4]) * di + bb1.x, 0.0f);
    float r5 = fmaxf((a0[5]+a1[5]+a2[5]+a3[5]) * di + bb1.y, 0.0f);
    float r6 = fmaxf((a0[6]+a1[6]+a2[6]+a3[6]) * di + bb1.z, 0.0f);
    float r7 = fmaxf((a0[7]+a1[7]+a2[7]+a3[7]) * di + bb1.w, 0.0f);
    uint4 o;
    o.x = pack2(r0, r1);
    o.y = pack2(r2, r3);
    o.z = pack2(r4, r5);
    o.w = pack2(r6, r7);
    *(uint4*)&Y[(size_t)n * 128 + f] = o;
}

// ---------------- mean-pool (fp16 Y): run-length over sorted batch ----------
#define NODES_PER_GROUP 100
__global__ __launch_bounds__(256) void pool_kernel(const __half* __restrict__ Y,
                                                   const int* __restrict__ batch,
                                                   float* __restrict__ pooled,
                                                   float* __restrict__ counts) {
    int g = (blockIdx.x * 256 + threadIdx.x) >> 5;
    int lane = threadIdx.x & 31;
    int f = lane * 4;
    int n0 = g * NODES_PER_GROUP;
    if (n0 >= N_NODES) return;
    int n1 = min(n0 + NODES_PER_GROUP, N_NODES);
    int cur = batch[n0];
    float4 acc = make_float4(0, 0, 0, 0);
    float cnt = 0.0f;
    for (int n = n0; n < n1; ++n) {
        int bid = batch[n];
        if (bid != cur) {
            float* p = &pooled[cur * 128 + f];
            atomicAdd(p + 0, acc.x); atomicAdd(p + 1, acc.y);
            atomicAdd(p + 2, acc.z); atomicAdd(p + 3, acc.w);
            if (lane == 0) atomicAdd(&counts[cur], cnt);
            acc = make_float4(0, 0, 0, 0); cnt = 0.0f; cur = bid;
        }
        uint2 w = *(const uint2*)&Y[(size_t)n * 128 + f];
        float2 p0 = __half22float2(*reinterpret_cast<__half2*>(&w.x));
        float2 p1 = __half22float2(*reinterpret_cast<__half2*>(&w.y));
        acc.x += p0.x; acc.y += p0.y; acc.z += p1.x; acc.w += p1.y;
        cnt += 1.0f;
    }
    float* p = &pooled[cur * 128 + f];
    atomicAdd(p + 0, acc.x); atomicAdd(p + 1, acc.y);
    atomicAdd(p + 2, acc.z); atomicAdd(p + 3, acc.w);
    if (lane == 0) atomicAdd(&counts[cur], cnt);
}

// ---------------- head: out[g] = dot(pooled[g], w_out)/count + b_out --------
__global__ __launch_bounds__(256) void out_kernel(const float* __restrict__ pooled,
                                                  const float* __restrict__ counts,
                                                  const float* __restrict__ w_out,
                                                  const float* __restrict__ b_out,
                                                  float* __restrict__ out) {
    int gph = threadIdx.x;
    float c = fmaxf(counts[gph], 1.0f);
    float s = 0.0f;
    for (int f = 0; f < 128; ++f) s += pooled[gph * 128 + f] * w_out[f];
    out[gph] = s / c + b_out[0];
}

extern "C" void kernel_launch(void* const* d_in, const int* in_sizes, int n_in,
                              void* d_out, int out_size, void* d_ws, size_t ws_size,
                              hipStream_t stream) {
    const float* x     = (const float*)d_in[0];
    const int*   edge  = (const int*)d_in[1];   // [2, E]
    const int*   batch = (const int*)d_in[2];
    const float* w1    = (const float*)d_in[3];
    const float* b1    = (const float*)d_in[4];
    const float* w2    = (const float*)d_in[5];
    const float* b2    = (const float*)d_in[6];
    const float* w_out = (const float*)d_in[7];
    const float* b_out = (const float*)d_in[8];
    float* out = (float*)d_out;

    char* ws = (char*)d_ws;
    size_t off = 0;
    auto alloc = [&](size_t bytes) {
        void* p = ws + off;
        off += (bytes + 511) & ~(size_t)511;
        return p;
    };
    const size_t FEAT_BYTES = (size_t)N_NODES * 128 * 4;     // 51.2 MB
    __half*   ht16       = (__half*)alloc(FEAT_BYTES / 2);   // 25.6 MB
    __half*   y16        = (__half*)alloc(FEAT_BYTES / 2);   // 25.6 MB (aliases pairbuf)
    unsigned* pairbuf    = (unsigned*)y16;                   // 8.0 MB, dead before first gather
    float*    dinv       = (float*)alloc(N_NODES * 4);
    int*      row_off    = (int*)alloc(N_NODES * 4);
    int*      csr_src    = (int*)alloc(N_EDGES * 4);         // 6.4 MB
    int*      bucket_cur = (int*)alloc((NB + 1) * 4);
    int*      bucket_off = (int*)alloc((NB + 1) * 4);
    __half*   wt1        = (__half*)alloc(128 * 128 * 2);
    __half*   wt2        = (__half*)alloc(128 * 128 * 2);
    float*    pooled     = (float*)alloc(N_GRAPHS * 128 * 4);
    float*    counts     = (float*)alloc(N_GRAPHS * 4);

    const int* src = edge;
    const int* dst = edge + N_EDGES;

    hipMemsetAsync(bucket_cur, 0, (NB + 1) * 4, stream);
    hipMemsetAsync(pooled, 0, N_GRAPHS * 128 * 4, stream);
    hipMemsetAsync(counts, 0, N_GRAPHS * 4, stream);

    // ----- weight prep (fp16, transposed) -----
    wprep_kernel<<<64, 256, 0, stream>>>(w1, wt1);
    wprep_kernel<<<64, 256, 0, stream>>>(w2, wt2);

    // ----- bucketed CSR build (no per-edge global atomics) -----
    stage_kernel<<<SBLOCKS, 1024, 0, stream>>>(src, dst, bucket_cur, pairbuf);
    scan_buckets_kernel<<<1, 256, 0, stream>>>(bucket_cur, bucket_off);
    localsort_kernel<<<NB, 256, 0, stream>>>(pairbuf, bucket_cur, bucket_off,
                                             csr_src, row_off, dinv);

    // ----- layer 1 -----
    int gblocks = (N_NODES + 127) / 128;
    gemm_mfma_kernel<<<gblocks, 256, 0, stream>>>(x, (const __half*)nullptr, wt1, dinv, ht16, 0);
    gather_kernel<<<(N_NODES * 16 + 255) / 256, 256, 0, stream>>>(row_off, csr_src, ht16, dinv, b1, y16);

    // ----- layer 2 -----
    gemm_mfma_kernel<<<gblocks, 256, 0, stream>>>((const float*)nullptr, y16, wt2, dinv, ht16, 1);
    gather_kernel<<<(N_NODES * 16 + 255) / 256, 256, 0, stream>>>(row_off, csr_src, ht16, dinv, b2, y16);

    // ----- pool + head -----
    int ngroups = (N_NODES + NODES_PER_GROUP - 1) / NODES_PER_GROUP;
    pool_kernel<<<(ngroups * 32 + 255) / 256, 256, 0, stream>>>(y16, batch, pooled, counts);
    out_kernel<<<1, 256, 0, stream>>>(pooled, counts, w_out, b_out, out);
}

// Round 10
// 235.974 us; speedup vs baseline: 5.8867x; 1.1162x over previous
//
#include <hip/hip_runtime.h>
#include <hip/hip_fp16.h>

#define N_NODES 100000
#define N_EDGES 1600000
#define N_GRAPHS 256
#define NB 1563              // ceil(100000 / 64) buckets of 64 nodes
#define SBLOCKS 256          // hist/scatter blocks; 6250 edges each
#define GB1 782              // gemm blocks for layer 1 (ceil(100000/128))

typedef _Float16 half8 __attribute__((ext_vector_type(8)));
typedef float f32x4 __attribute__((ext_vector_type(4)));

__device__ __forceinline__ unsigned pack2(float a, float b) {
    __half2 h = __floats2half2_rn(a, b);
    return *reinterpret_cast<unsigned*>(&h);
}

// ---------------- W prep: Wt16[n][k] = fp16(W[k][n]), both weights ----------
__global__ __launch_bounds__(256) void wprep_kernel(const float* __restrict__ W1,
                                                    const float* __restrict__ W2,
                                                    __half* __restrict__ Wt1,
                                                    __half* __restrict__ Wt2) {
    int b = blockIdx.x;
    const float* W = (b < 64) ? W1 : W2;
    __half* Wt = (b < 64) ? Wt1 : Wt2;
    int t = (b & 63) * 256 + threadIdx.x;   // 0..16383
    int n = t >> 7, k = t & 127;
    Wt[t] = (__half)W[k * 128 + n];
}

// ---------------- fused MFMA-GEMM / edge-histogram kernel -------------------
// histBlocks!=0: grid 1038; blocks b%4==0 (b<1024) run hist id=b>>2 (256 of
// them, interleaved so they overlap the gemm blocks); others run gemm tiles
// id 0..781. hist: per-block LDS histogram of dst>>6 -> cnt2d[id*NB+i], NO
// global atomics (kills R4's 230ns*depth reservation serialization).
// gemm: 128 rows/block, 4 waves, mfma_f32_16x16x32_f16 (layouts HW-verified
// guide s3); withDinv=0 stores raw XW (dinv deferred to gather's DV path).
__global__ __launch_bounds__(256) void gemmhist_kernel(const float* __restrict__ Xf,
                                                       const __half* __restrict__ Xh,
                                                       const __half* __restrict__ Wt,
                                                       const float* __restrict__ dinv,
                                                       __half* __restrict__ HT,
                                                       int xf16, int withDinv,
                                                       const int* __restrict__ dst,
                                                       int* __restrict__ cnt2d,
                                                       int histBlocks) {
    __shared__ __align__(16) char smem[69632];
    const int tid = threadIdx.x;
    int bid = blockIdx.x;
    bool isHist = false;
    int id = bid;
    if (histBlocks) {
        if (bid < 1024) {
            if ((bid & 3) == 0) { isHist = true; id = bid >> 2; }
            else id = (bid >> 2) * 3 + (bid & 3) - 1;
        } else {
            id = 768 + (bid - 1024);
        }
    }

    if (isHist) {
        int* lcnt = (int*)smem;
        for (int i = tid; i < NB; i += 256) lcnt[i] = 0;
        __syncthreads();
        const int per = (N_EDGES + SBLOCKS - 1) / SBLOCKS;   // 6250
        int e0 = id * per, e1 = min(e0 + per, N_EDGES);
        for (int e = e0 + tid; e < e1; e += 256)
            atomicAdd(&lcnt[dst[e] >> 6], 1);
        __syncthreads();
        for (int i = tid; i < NB; i += 256)
            cnt2d[id * NB + i] = lcnt[i];                    // coalesced row
        return;
    }

    typedef __half (*TileT)[136];
    TileT Xl = (TileT)smem;                  // 128 x 136 halves
    TileT Wl = (TileT)(smem + 34816);        // 128 x 136 halves
    const int row0 = id * 128;

#pragma unroll
    for (int i = 0; i < 8; ++i) {
        int idx = tid + i * 256;             // 0..2047
        int n = idx >> 4, c0 = (idx & 15) * 8;
        *(uint4*)&Wl[n][c0] = *(const uint4*)&Wt[n * 128 + c0];
    }
    if (xf16) {
#pragma unroll
        for (int i = 0; i < 8; ++i) {
            int idx = tid + i * 256;
            int r = idx >> 4, c0 = (idx & 15) * 8;
            int rr = min(row0 + r, N_NODES - 1);
            *(uint4*)&Xl[r][c0] = *(const uint4*)&Xh[(size_t)rr * 128 + c0];
        }
    } else {
#pragma unroll
        for (int i = 0; i < 16; ++i) {
            int idx = tid + i * 256;         // 0..4095
            int r = idx >> 5, c0 = (idx & 31) * 4;
            int rr = min(row0 + r, N_NODES - 1);
            float4 v = *(const float4*)&Xf[(size_t)rr * 128 + c0];
            uint2 o;
            o.x = pack2(v.x, v.y);
            o.y = pack2(v.z, v.w);
            *(uint2*)&Xl[r][c0] = o;
        }
    }
    __syncthreads();

    const int wv = tid >> 6;
    const int lane = tid & 63;
    const int lr = lane & 15;
    const int lg = lane >> 4;

    f32x4 acc[2][8];
#pragma unroll
    for (int mt = 0; mt < 2; ++mt)
#pragma unroll
        for (int nt = 0; nt < 8; ++nt) acc[mt][nt] = (f32x4){0.f, 0.f, 0.f, 0.f};

#pragma unroll
    for (int ks = 0; ks < 4; ++ks) {
        const int kb = ks * 32 + lg * 8;
        half8 a0 = *reinterpret_cast<const half8*>(&Xl[wv * 32 + lr][kb]);
        half8 a1 = *reinterpret_cast<const half8*>(&Xl[wv * 32 + 16 + lr][kb]);
        half8 b[8];
#pragma unroll
        for (int nt = 0; nt < 8; ++nt)
            b[nt] = *reinterpret_cast<const half8*>(&Wl[nt * 16 + lr][kb]);
#pragma unroll
        for (int nt = 0; nt < 8; ++nt) {
            acc[0][nt] = __builtin_amdgcn_mfma_f32_16x16x32_f16(a0, b[nt], acc[0][nt], 0, 0, 0);
            acc[1][nt] = __builtin_amdgcn_mfma_f32_16x16x32_f16(a1, b[nt], acc[1][nt], 0, 0, 0);
        }
    }

#pragma unroll
    for (int mt = 0; mt < 2; ++mt) {
#pragma unroll
        for (int i = 0; i < 4; ++i) {
            int rr = row0 + wv * 32 + mt * 16 + lg * 4 + i;
            if (rr < N_NODES) {
                float di = withDinv ? dinv[rr] : 1.0f;
#pragma unroll
                for (int nt = 0; nt < 8; ++nt)
                    HT[(size_t)rr * 128 + nt * 16 + lr] = (__half)(acc[mt][nt][i] * di);
            }
        }
    }
}

// ---------------- scan2d: exclusive scan of cnt2d along block dim -----------
__global__ __launch_bounds__(256) void scan2d_kernel(int* __restrict__ cnt2d,
                                                     int* __restrict__ bucket_cnt) {
    __shared__ int ts[256];
    int i = blockIdx.x;       // bucket
    int t = threadIdx.x;      // hist-block index
    int v = cnt2d[t * NB + i];
    ts[t] = v;
    __syncthreads();
    for (int off = 1; off < 256; off <<= 1) {
        int y = (t >= off) ? ts[t - off] : 0;
        __syncthreads();
        ts[t] += y;
        __syncthreads();
    }
    cnt2d[t * NB + i] = ts[t] - v;   // exclusive
    if (t == 255) bucket_cnt[i] = ts[255];
}

// ---------------- scanB: exclusive scan over bucket totals ------------------
#define BVPT 7   // 256*7 = 1792 >= NB
__global__ __launch_bounds__(256) void scanB_kernel(const int* __restrict__ bucket_cnt,
                                                    int* __restrict__ bucket_off) {
    __shared__ int tsum[256];
    int tid = threadIdx.x;
    int v[BVPT];
    int s = 0;
#pragma unroll
    for (int j = 0; j < BVPT; ++j) {
        int idx = tid * BVPT + j;
        v[j] = (idx < NB) ? bucket_cnt[idx] : 0;
        s += v[j];
    }
    tsum[tid] = s;
    __syncthreads();
    for (int off = 1; off < 256; off <<= 1) {
        int y = (tid >= off) ? tsum[tid - off] : 0;
        __syncthreads();
        tsum[tid] += y;
        __syncthreads();
    }
    int run = (tid > 0) ? tsum[tid - 1] : 0;
#pragma unroll
    for (int j = 0; j < BVPT; ++j) {
        int idx = tid * BVPT + j;
        if (idx < NB) bucket_off[idx] = run;
        run += v[j];
    }
    if (tid == 255) bucket_off[NB] = tsum[255];
}

// ---------------- scatter: exact-packed bucket scatter (LDS cursors) --------
__global__ __launch_bounds__(256) void scatter_kernel(const int* __restrict__ src,
                                                      const int* __restrict__ dst,
                                                      const int* __restrict__ cnt2d,
                                                      const int* __restrict__ bucket_off,
                                                      unsigned* __restrict__ pairbuf) {
    __shared__ int lcur[NB];
    const int tid = threadIdx.x;
    const int blk = blockIdx.x;
    for (int i = tid; i < NB; i += 256)
        lcur[i] = bucket_off[i] + cnt2d[blk * NB + i];
    __syncthreads();
    const int per = (N_EDGES + SBLOCKS - 1) / SBLOCKS;
    int e0 = blk * per, e1 = min(e0 + per, N_EDGES);
    for (int e = e0 + tid; e < e1; e += 256) {
        int d = dst[e];
        int b = d >> 6;
        int p = atomicAdd(&lcur[b], 1);
        pairbuf[p] = ((unsigned)(d & 63) << 17) | (unsigned)src[e];
    }
}

// ---------------- per-bucket counting sort -> csr/row_off/dinv --------------
__global__ __launch_bounds__(256) void localsort_kernel(const unsigned* __restrict__ pairbuf,
                                                        const int* __restrict__ bucket_off,
                                                        int* __restrict__ csr_src,
                                                        int* __restrict__ row_off,
                                                        float* __restrict__ dinv) {
    __shared__ int ldeg[64];
    __shared__ int loff[64];
    __shared__ int lcur[64];
    int tid = threadIdx.x;
    int b = blockIdx.x;
    int base = bucket_off[b];
    int cnt = bucket_off[b + 1] - base;
    const unsigned* pb = pairbuf + base;
    int n0 = b << 6;

    if (tid < 64) ldeg[tid] = 0;
    __syncthreads();
    for (int i = tid; i < cnt; i += 256)
        atomicAdd(&ldeg[pb[i] >> 17], 1);
    __syncthreads();
    if (tid < 64) loff[tid] = ldeg[tid];
    __syncthreads();
    for (int off = 1; off < 64; off <<= 1) {
        int y = 0;
        if (tid < 64 && tid >= off) y = loff[tid - off];
        __syncthreads();
        if (tid < 64) loff[tid] += y;
        __syncthreads();
    }
    if (tid < 64) {
        int ex = loff[tid] - ldeg[tid];
        lcur[tid] = ex;
        int n = n0 + tid;
        if (n < N_NODES) {
            row_off[n] = base + ex;
            dinv[n] = rsqrtf((float)ldeg[tid] + 1.0f);
        }
    }
    __syncthreads();
    for (int i = tid; i < cnt; i += 256) {
        unsigned w = pb[i];
        int dl = w >> 17;
        int s = (int)(w & 0x1FFFFu);
        int p = atomicAdd(&lcur[dl], 1);
        csr_src[base + p] = s;
    }
}

// ---------------- gather (template DV) --------------------------------------
// DV=true (layer 1): ht holds raw XW; accumulate dinv[s]*ht[s] via fma.
// DV=false (layer 2): ht has dinv folded; plain adds. 16 lanes/node, 16B/lane,
// unroll-4 independent accumulator sets (MLP), fp32 accumulate.
__device__ __forceinline__ void add8(float* a, uint4 w) {
    float2 p0 = __half22float2(*reinterpret_cast<__half2*>(&w.x));
    float2 p1 = __half22float2(*reinterpret_cast<__half2*>(&w.y));
    float2 p2 = __half22float2(*reinterpret_cast<__half2*>(&w.z));
    float2 p3 = __half22float2(*reinterpret_cast<__half2*>(&w.w));
    a[0] += p0.x; a[1] += p0.y; a[2] += p1.x; a[3] += p1.y;
    a[4] += p2.x; a[5] += p2.y; a[6] += p3.x; a[7] += p3.y;
}
__device__ __forceinline__ void fma8(float* a, uint4 w, float s) {
    float2 p0 = __half22float2(*reinterpret_cast<__half2*>(&w.x));
    float2 p1 = __half22float2(*reinterpret_cast<__half2*>(&w.y));
    float2 p2 = __half22float2(*reinterpret_cast<__half2*>(&w.z));
    float2 p3 = __half22float2(*reinterpret_cast<__half2*>(&w.w));
    a[0] = fmaf(s, p0.x, a[0]); a[1] = fmaf(s, p0.y, a[1]);
    a[2] = fmaf(s, p1.x, a[2]); a[3] = fmaf(s, p1.y, a[3]);
    a[4] = fmaf(s, p2.x, a[4]); a[5] = fmaf(s, p2.y, a[5]);
    a[6] = fmaf(s, p3.x, a[6]); a[7] = fmaf(s, p3.y, a[7]);
}
template<bool DV>
__global__ __launch_bounds__(256) void gather_kernel(const int* __restrict__ row_off,
                                                     const int* __restrict__ csr_src,
                                                     const __half* __restrict__ ht,
                                                     const float* __restrict__ dinv,
                                                     const float* __restrict__ bias,
                                                     __half* __restrict__ Y) {
    int t = blockIdx.x * 256 + threadIdx.x;
    int n = t >> 4;
    if (n >= N_NODES) return;
    int f = (t & 15) * 8;
    int e0 = row_off[n];
    int e1 = (n < N_NODES - 1) ? row_off[n + 1] : N_EDGES;
    const __half* htf = ht + f;
    float dn = dinv[n];

    float a0[8] = {0,0,0,0,0,0,0,0};
    float a1[8] = {0,0,0,0,0,0,0,0};
    float a2[8] = {0,0,0,0,0,0,0,0};
    float a3[8] = {0,0,0,0,0,0,0,0};
    {   // self-loop term
        uint4 w = *(const uint4*)&htf[(size_t)n * 128];
        if (DV) fma8(a0, w, dn); else add8(a0, w);
    }
    int e = e0;
    for (; e + 4 <= e1; e += 4) {
        int s0 = csr_src[e], s1 = csr_src[e + 1];
        int s2 = csr_src[e + 2], s3 = csr_src[e + 3];
        uint4 w0 = *(const uint4*)&htf[(size_t)s0 * 128];
        uint4 w1 = *(const uint4*)&htf[(size_t)s1 * 128];
        uint4 w2 = *(const uint4*)&htf[(size_t)s2 * 128];
        uint4 w3 = *(const uint4*)&htf[(size_t)s3 * 128];
        if (DV) {
            fma8(a0, w0, dinv[s0]); fma8(a1, w1, dinv[s1]);
            fma8(a2, w2, dinv[s2]); fma8(a3, w3, dinv[s3]);
        } else {
            add8(a0, w0); add8(a1, w1); add8(a2, w2); add8(a3, w3);
        }
    }
    for (; e < e1; ++e) {
        int s = csr_src[e];
        uint4 w = *(const uint4*)&htf[(size_t)s * 128];
        if (DV) fma8(a0, w, dinv[s]); else add8(a0, w);
    }

    float4 bb0 = *(const float4*)&bias[f];
    float4 bb1 = *(const float4*)&bias[f + 4];
    float r0 = fmaxf((a0[0]+a1[0]+a2[0]+a3[0]) * dn + bb0.x, 0.0f);
    float r1 = fmaxf((a0[1]+a1[1]+a2[1]+a3[1]) * dn + bb0.y, 0.0f);
    float r2 = fmaxf((a0[2]+a1[2]+a2[2]+a3[2]) * dn + bb0.z, 0.0f);
    float r3 = fmaxf((a0[3]+a1[3]+a2[3]+a3[3]) * dn + bb0.w, 0.0f);
    float r4 = fmaxf((a0[4]+a1[4]+a2[4]+a3[4]) * dn + bb1.x, 0.0f);
    float r5 = fmaxf((a0[5]+a1[5]+a2[5]+a3[5]) * dn + bb1.y, 0.0f);
    float r6 = fmaxf((a0[6]+a1[6]+a2[6]+a3[6]) * dn + bb1.z, 0.0f);
    float r7 = fmaxf((a0[7]+a1[7]+a2[7]+a3[7]) * dn + bb1.w, 0.0f);
    uint4 o;
    o.x = pack2(r0, r1);
    o.y = pack2(r2, r3);
    o.z = pack2(r4, r5);
    o.w = pack2(r6, r7);
    *(uint4*)&Y[(size_t)n * 128 + f] = o;
}

// ---------------- fused mean-pool + head: one block per graph ---------------
// batch is sorted: binary-search [lo,hi) for graph g, stream rows, LDS-reduce,
// dot with w_out, write out[g]. No atomics, no memsets, replaces pool+out.
__global__ __launch_bounds__(256) void poolout_kernel(const __half* __restrict__ Y,
                                                      const int* __restrict__ batch,
                                                      const float* __restrict__ w_out,
                                                      const float* __restrict__ b_out,
                                                      float* __restrict__ out) {
    __shared__ float red[8][128];
    __shared__ float pr[128];
    int g = blockIdx.x;
    int tid = threadIdx.x;
    // lower bound for g and g+1 (all threads redundantly; uniform)
    int lo = 0, hi = N_NODES;
    while (lo < hi) { int m = (lo + hi) >> 1; if (batch[m] < g) lo = m + 1; else hi = m; }
    int lo2 = lo, hi2 = N_NODES;
    while (lo2 < hi2) { int m = (lo2 + hi2) >> 1; if (batch[m] < g + 1) lo2 = m + 1; else hi2 = m; }
    int cnt = lo2 - lo;

    int rslot = tid >> 5;          // 0..7
    int f = (tid & 31) * 4;
    float4 acc = make_float4(0, 0, 0, 0);
    for (int n = lo + rslot; n < lo2; n += 8) {
        uint2 w = *(const uint2*)&Y[(size_t)n * 128 + f];
        float2 p0 = __half22float2(*reinterpret_cast<__half2*>(&w.x));
        float2 p1 = __half22float2(*reinterpret_cast<__half2*>(&w.y));
        acc.x += p0.x; acc.y += p0.y; acc.z += p1.x; acc.w += p1.y;
    }
    *(float4*)&red[rslot][f] = acc;
    __syncthreads();
    if (tid < 128) {
        float s = 0.0f;
#pragma unroll
        for (int r = 0; r < 8; ++r) s += red[r][tid];
        pr[tid] = s * w_out[tid];
    }
    __syncthreads();
    for (int off = 64; off >= 1; off >>= 1) {
        if (tid < off) pr[tid] += pr[tid + off];
        __syncthreads();
    }
    if (tid == 0)
        out[g] = pr[0] / fmaxf((float)cnt, 1.0f) + b_out[0];
}

extern "C" void kernel_launch(void* const* d_in, const int* in_sizes, int n_in,
                              void* d_out, int out_size, void* d_ws, size_t ws_size,
                              hipStream_t stream) {
    const float* x     = (const float*)d_in[0];
    const int*   edge  = (const int*)d_in[1];   // [2, E]
    const int*   batch = (const int*)d_in[2];
    const float* w1    = (const float*)d_in[3];
    const float* b1    = (const float*)d_in[4];
    const float* w2    = (const float*)d_in[5];
    const float* b2    = (const float*)d_in[6];
    const float* w_out = (const float*)d_in[7];
    const float* b_out = (const float*)d_in[8];
    float* out = (float*)d_out;

    char* ws = (char*)d_ws;
    size_t off = 0;
    auto alloc = [&](size_t bytes) {
        void* p = ws + off;
        off += (bytes + 511) & ~(size_t)511;
        return p;
    };
    const size_t FEAT_BYTES = (size_t)N_NODES * 128 * 4;     // 51.2 MB
    __half*   ht16       = (__half*)alloc(FEAT_BYTES / 2);   // 25.6 MB
    __half*   y16        = (__half*)alloc(FEAT_BYTES / 2);   // 25.6 MB (aliases pairbuf)
    unsigned* pairbuf    = (unsigned*)y16;                   // 6.4 MB, dead after localsort
    float*    dinv       = (float*)alloc(N_NODES * 4);
    int*      row_off    = (int*)alloc(N_NODES * 4);
    int*      csr_src    = (int*)alloc(N_EDGES * 4);         // 6.4 MB
    int*      cnt2d      = (int*)alloc((size_t)SBLOCKS * NB * 4);  // 1.6 MB
    int*      bucket_cnt = (int*)alloc((NB + 1) * 4);
    int*      bucket_off = (int*)alloc((NB + 1) * 4);
    __half*   wt1        = (__half*)alloc(128 * 128 * 2);
    __half*   wt2        = (__half*)alloc(128 * 128 * 2);

    const int* src = edge;
    const int* dst = edge + N_EDGES;

    // ----- weight prep (both, one launch) -----
    wprep_kernel<<<128, 256, 0, stream>>>(w1, w2, wt1, wt2);

    // ----- K1: layer-1 GEMM (raw XW, dinv deferred) fused with edge hist ----
    gemmhist_kernel<<<1024 + (GB1 - 768), 256, 0, stream>>>(
        x, (const __half*)nullptr, wt1, (const float*)nullptr, ht16,
        0, 0, dst, cnt2d, 1);

    // ----- CSR build: scan2d -> scanB -> scatter -> localsort ---------------
    scan2d_kernel<<<NB, 256, 0, stream>>>(cnt2d, bucket_cnt);
    scanB_kernel<<<1, 256, 0, stream>>>(bucket_cnt, bucket_off);
    scatter_kernel<<<SBLOCKS, 256, 0, stream>>>(src, dst, cnt2d, bucket_off, pairbuf);
    localsort_kernel<<<NB, 256, 0, stream>>>(pairbuf, bucket_off, csr_src, row_off, dinv);

    // ----- layer 1 gather (applies dinv[s] per edge) -----
    gather_kernel<true><<<(N_NODES * 16 + 255) / 256, 256, 0, stream>>>(
        row_off, csr_src, ht16, dinv, b1, y16);

    // ----- layer 2 -----
    gemmhist_kernel<<<GB1, 256, 0, stream>>>(
        (const float*)nullptr, y16, wt2, dinv, ht16, 1, 1,
        (const int*)nullptr, (int*)nullptr, 0);
    gather_kernel<false><<<(N_NODES * 16 + 255) / 256, 256, 0, stream>>>(
        row_off, csr_src, ht16, dinv, b2, y16);

    // ----- fused pool + head -----
    poolout_kernel<<<N_GRAPHS, 256, 0, stream>>>(y16, batch, w_out, b_out, out);
}